// Round 2
// baseline (354.013 us; speedup 1.0000x reference)
//
#include <hip/hip_runtime.h>

// SSIM fused kernel, round 2: packed-fp32 (v_pk_fma_f32) blur chains + NSEG=16.
// B=16, C=3, H=W=768, 11-tap separable Gaussian, VALID -> 758x758; out = per-batch mean [16].
//
// Stage A: horizontal blur, quantities packed as (x,y) / (x^2,y^2) f32x2 chains + xy scalar.
// Stage B: vertical blur via per-thread f32x2 register rings (14-deep), 4 rows/macro-iter.

typedef float f32x2 __attribute__((ext_vector_type(2)));
typedef float f32x4 __attribute__((ext_vector_type(4)));

#define H_IMG 768
#define W_IMG 768
#define OH 758
#define OW_TOT 758
#define OWS 256   // output cols per strip
#define NSEG 16   // vertical segments

static __device__ __forceinline__ f32x2 mk2(float a, float b) {
    f32x2 r; r.x = a; r.y = b; return r;
}
static __device__ __forceinline__ f32x4 mk4(float a, float b, float c, float d) {
    f32x4 r; r.x = a; r.y = b; r.z = c; r.w = d; return r;
}

__global__ void ssim_zero_out(float* __restrict__ out) {
    if (threadIdx.x < 16) out[threadIdx.x] = 0.0f;
}

__launch_bounds__(256, 4)
__global__ void ssim_fused(const float* __restrict__ X, const float* __restrict__ Y,
                           const float* __restrict__ Wg, float* __restrict__ out) {
    const float C1 = 1e-4f, C2 = 9e-4f, EPS = 1e-8f;
    const float INV_COUNT = 1.0f / (3.0f * 758.0f * 758.0f);

    const int t = threadIdx.x;
    int bx = blockIdx.x;
    const int seg = bx & (NSEG - 1); bx >>= 4;
    const int strip = bx % 3; bx /= 3;
    const int ch = bx % 3;
    const int b  = bx / 3;

    const int R0 = (OH * seg) / NSEG;
    const int R1 = (OH * (seg + 1)) / NSEG;
    const int c0 = strip * OWS;

    const float* Xi = X + (size_t)(b * 3 + ch) * (H_IMG * W_IMG);
    const float* Yi = Y + (size_t)(b * 3 + ch) * (H_IMG * W_IMG);

    float w[11];
#pragma unroll
    for (int k = 0; k < 11; ++k) w[k] = Wg[k];

    // LDS handoff: (x,y) blur pair, (x^2,y^2) blur pair, xy blur scalar.
    __shared__ __align__(16) f32x2 hxyL[4][OWS];  // 8 KB
    __shared__ __align__(16) f32x2 hsqL[4][OWS];  // 8 KB
    __shared__ __align__(16) float hpL[4][OWS];   // 4 KB
    __shared__ float red[4];

    // Stage A mapping: 4 rows x 64 col-groups (4 cols each)
    const int sA = t >> 6;
    const int cg = t & 63;
    const int colbase = c0 + 4 * cg;
    const int k0 = min(colbase,      W_IMG - 4);
    const int k1 = min(colbase + 4,  W_IMG - 4);
    const int k2 = min(colbase + 8,  W_IMG - 4);
    const int k3 = min(colbase + 12, W_IMG - 2);

    // Stage B register rings (14 h-rows): packed pairs + scalar
    f32x2 r01[14], r23[14];
    float r4[14];
#pragma unroll
    for (int j = 0; j < 14; ++j) { r01[j] = mk2(0.f, 0.f); r23[j] = mk2(0.f, 0.f); r4[j] = 0.f; }

    float local = 0.0f;
    const int M = (R1 - R0 + 13) >> 2;

    for (int m = 0; m < M; ++m) {
        // ---------------- Stage A: horizontal blur (packed) ----------------
        {
            int r = R0 + 4 * m + sA;
            r = min(r, H_IMG - 1);
            const float* xr = Xi + (size_t)r * W_IMG;
            const float* yr = Yi + (size_t)r * W_IMG;
            float4 xa = *(const float4*)(xr + k0);
            float4 xb = *(const float4*)(xr + k1);
            float4 xc = *(const float4*)(xr + k2);
            float2 xd = *(const float2*)(xr + k3);
            float4 ya = *(const float4*)(yr + k0);
            float4 yb = *(const float4*)(yr + k1);
            float4 yc = *(const float4*)(yr + k2);
            float2 yd = *(const float2*)(yr + k3);
            float xv[14] = {xa.x, xa.y, xa.z, xa.w, xb.x, xb.y, xb.z, xb.w,
                            xc.x, xc.y, xc.z, xc.w, xd.x, xd.y};
            float yv[14] = {ya.x, ya.y, ya.z, ya.w, yb.x, yb.y, yb.z, yb.w,
                            yc.x, yc.y, yc.z, yc.w, yd.x, yd.y};

            f32x2 vxy[14], vsq[14];
            float vp[14];
#pragma unroll
            for (int j = 0; j < 14; ++j) {
                vxy[j] = mk2(xv[j], yv[j]);
                vp[j]  = xv[j] * yv[j];
                vsq[j] = vxy[j] * vxy[j];
            }

            f32x2 hxyA[4], hsqA[4];
            float hpA[4];
#pragma unroll
            for (int cc = 0; cc < 4; ++cc) {
                f32x2 hxy = mk2(0.f, 0.f), hsq = mk2(0.f, 0.f);
                float hp = 0.f;
#pragma unroll
                for (int k = 0; k < 11; ++k) {
                    f32x2 ww = mk2(w[k], w[k]);
                    hxy = __builtin_elementwise_fma(ww, vxy[cc + k], hxy);
                    hsq = __builtin_elementwise_fma(ww, vsq[cc + k], hsq);
                    hp  = fmaf(w[k], vp[cc + k], hp);
                }
                hxyA[cc] = hxy; hsqA[cc] = hsq; hpA[cc] = hp;
            }
            *(f32x4*)&hxyL[sA][4 * cg]     = mk4(hxyA[0].x, hxyA[0].y, hxyA[1].x, hxyA[1].y);
            *(f32x4*)&hxyL[sA][4 * cg + 2] = mk4(hxyA[2].x, hxyA[2].y, hxyA[3].x, hxyA[3].y);
            *(f32x4*)&hsqL[sA][4 * cg]     = mk4(hsqA[0].x, hsqA[0].y, hsqA[1].x, hsqA[1].y);
            *(f32x4*)&hsqL[sA][4 * cg + 2] = mk4(hsqA[2].x, hsqA[2].y, hsqA[3].x, hsqA[3].y);
            *(f32x4*)&hpL[sA][4 * cg]      = mk4(hpA[0], hpA[1], hpA[2], hpA[3]);
        }
        __syncthreads();

        // ---------------- Stage B: vertical blur + SSIM ----------------
        {
#pragma unroll
            for (int j = 0; j < 10; ++j) {
                r01[j] = r01[j + 4];
                r23[j] = r23[j + 4];
                r4[j]  = r4[j + 4];
            }
#pragma unroll
            for (int s2 = 0; s2 < 4; ++s2) {
                r01[10 + s2] = hxyL[s2][t];
                r23[10 + s2] = hsqL[s2][t];
                r4[10 + s2]  = hpL[s2][t];
            }

            const bool colok = (c0 + t) < OW_TOT;
#pragma unroll
            for (int s2 = 0; s2 < 4; ++s2) {
                const int orow = R0 + 4 * m - 10 + s2;
                f32x2 a01 = mk2(0.f, 0.f), a23 = mk2(0.f, 0.f);
                float a4 = 0.f;
#pragma unroll
                for (int k = 0; k < 11; ++k) {
                    f32x2 ww = mk2(w[k], w[k]);
                    a01 = __builtin_elementwise_fma(ww, r01[s2 + k], a01);
                    a23 = __builtin_elementwise_fma(ww, r23[s2 + k], a23);
                    a4  = fmaf(w[k], r4[s2 + k], a4);
                }
                float a0 = a01.x, a1 = a01.y, a2 = a23.x, a3 = a23.y;
                float sx  = a2 - a0 * a0;
                float sy  = a3 - a1 * a1;
                float sxy = a4 - a0 * a1;
                float cs = __fdividef(2.0f * sxy + C2, sx + sy + C2 + EPS);
                cs = fmaxf(cs, 0.0f);
                float l = __fdividef(2.0f * a0 * a1 + C1,
                                     a0 * a0 + a1 * a1 + C1 + EPS);
                float v = l * cs;
                if (colok && (orow >= R0) && (orow < R1)) local += v;
            }
        }
        __syncthreads();
    }

    // ---------------- block reduction + atomic ----------------
    float v = local;
#pragma unroll
    for (int off = 32; off > 0; off >>= 1) v += __shfl_down(v, off, 64);
    if ((t & 63) == 0) red[t >> 6] = v;
    __syncthreads();
    if (t == 0) {
        atomicAdd(&out[b], (red[0] + red[1] + red[2] + red[3]) * INV_COUNT);
    }
}

extern "C" void kernel_launch(void* const* d_in, const int* in_sizes, int n_in,
                              void* d_out, int out_size, void* d_ws, size_t ws_size,
                              hipStream_t stream) {
    const float* X  = (const float*)d_in[0];
    const float* Y  = (const float*)d_in[1];
    const float* Wg = (const float*)d_in[2];
    float* out = (float*)d_out;

    hipLaunchKernelGGL(ssim_zero_out, dim3(1), dim3(64), 0, stream, out);
    hipLaunchKernelGGL(ssim_fused, dim3(16 * 3 * 3 * NSEG), dim3(256), 0, stream,
                       X, Y, Wg, out);
}

// Round 3
// 325.797 us; speedup vs baseline: 1.0866x; 1.0866x over previous
//
#include <hip/hip_runtime.h>

// SSIM fused kernel, round 3.
// B=16, C=3, H=W=768, 11-tap separable Gaussian, VALID -> 758x758; out = per-batch mean [16].
//
// Changes vs R2:
//  - 4-field algebra: blur {x, y, x^2+y^2, x*y} only (sigma_x+sigma_y from one chain).
//  - Ring-16 vertical buffer with period-4 unrolled macro-loop: static slot indices,
//    zero shift moves.
//  - amdgpu_waves_per_eu(3,3): 168-VGPR budget so ring lives in arch VGPRs
//    (R1/R2 showed the 64-VGPR heuristic causing AGPR-copy/scratch-spill tax).
//  - Scalar fp32, b32 LDS layout (R1: 0 bank conflicts), single fdividef.

#define H_IMG 768
#define W_IMG 768
#define OH 758
#define OW_TOT 758
#define OWS 256   // output cols per strip
#define NSEG 16   // vertical segments

__global__ void ssim_zero_out(float* __restrict__ out) {
    if (threadIdx.x < 16) out[threadIdx.x] = 0.0f;
}

__attribute__((amdgpu_flat_work_group_size(256, 256), amdgpu_waves_per_eu(3, 3)))
__global__ void ssim_fused(const float* __restrict__ X, const float* __restrict__ Y,
                           const float* __restrict__ Wg, float* __restrict__ out) {
    const float C1 = 1e-4f, C2 = 9e-4f, EPS = 1e-8f;
    const float INV_COUNT = 1.0f / (3.0f * 758.0f * 758.0f);

    const int t = threadIdx.x;
    int bx = blockIdx.x;
    const int seg = bx & (NSEG - 1); bx >>= 4;
    const int strip = bx % 3; bx /= 3;
    const int ch = bx % 3;
    const int b  = bx / 3;

    const int R0 = (OH * seg) / NSEG;
    const int Rend = (OH * (seg + 1)) / NSEG;
    const int hseg = Rend - R0;
    const int c0 = strip * OWS;

    const float* Xi = X + (size_t)(b * 3 + ch) * (H_IMG * W_IMG);
    const float* Yi = Y + (size_t)(b * 3 + ch) * (H_IMG * W_IMG);

    float w[11];
#pragma unroll
    for (int k = 0; k < 11; ++k) w[k] = Wg[k];

    // LDS handoff: [4 stage-A rows][4 fields: mux,muy,sum_sq,prod][256 cols]
    __shared__ float hb[4][4][OWS];   // 16 KB
    __shared__ float red[4];

    // Stage A mapping: 4 rows x 64 col-groups (4 cols each)
    const int sA = t >> 6;
    const int cg = t & 63;
    const int colbase = c0 + 4 * cg;
    const int k0 = min(colbase,      W_IMG - 4);
    const int k1 = min(colbase + 4,  W_IMG - 4);
    const int k2 = min(colbase + 8,  W_IMG - 4);
    const int k3 = min(colbase + 12, W_IMG - 2);

    // Stage B: ring-16 per field. Slot of h-row (rel r) = r & 15.
    float rg[4][16];
#pragma unroll
    for (int f = 0; f < 4; ++f)
#pragma unroll
        for (int j = 0; j < 16; ++j) rg[f][j] = 0.0f;

    const bool colok = (c0 + t) < OW_TOT;
    float local = 0.0f;
    const int M = (hseg + 13) >> 2;   // macro-iters of 4 input rows

    for (int mb = 0; mb < M; mb += 4) {
#pragma unroll
        for (int p = 0; p < 4; ++p) {
            const int m = mb + p;
            if (m < M) {
                // ---------------- Stage A: horizontal blur ----------------
                {
                    int r = R0 + 4 * m + sA;
                    r = min(r, H_IMG - 1);
                    const float* xr = Xi + (size_t)r * W_IMG;
                    const float* yr = Yi + (size_t)r * W_IMG;
                    float4 xa = *(const float4*)(xr + k0);
                    float4 xb = *(const float4*)(xr + k1);
                    float4 xc = *(const float4*)(xr + k2);
                    float2 xd = *(const float2*)(xr + k3);
                    float4 ya = *(const float4*)(yr + k0);
                    float4 yb = *(const float4*)(yr + k1);
                    float4 yc = *(const float4*)(yr + k2);
                    float2 yd = *(const float2*)(yr + k3);
                    float xv[14] = {xa.x, xa.y, xa.z, xa.w, xb.x, xb.y, xb.z, xb.w,
                                    xc.x, xc.y, xc.z, xc.w, xd.x, xd.y};
                    float yv[14] = {ya.x, ya.y, ya.z, ya.w, yb.x, yb.y, yb.z, yb.w,
                                    yc.x, yc.y, yc.z, yc.w, yd.x, yd.y};
                    float sv[14], pv[14];
#pragma unroll
                    for (int j = 0; j < 14; ++j) {
                        pv[j] = xv[j] * yv[j];
                        sv[j] = fmaf(xv[j], xv[j], yv[j] * yv[j]);
                    }
                    float h0[4], h1[4], h2[4], h3[4];
#pragma unroll
                    for (int cc = 0; cc < 4; ++cc) {
                        float a0 = 0.f, a1 = 0.f, a2 = 0.f, a3 = 0.f;
#pragma unroll
                        for (int k = 0; k < 11; ++k) {
                            a0 = fmaf(w[k], xv[cc + k], a0);
                            a1 = fmaf(w[k], yv[cc + k], a1);
                            a2 = fmaf(w[k], sv[cc + k], a2);
                            a3 = fmaf(w[k], pv[cc + k], a3);
                        }
                        h0[cc] = a0; h1[cc] = a1; h2[cc] = a2; h3[cc] = a3;
                    }
                    *(float4*)&hb[sA][0][4 * cg] = make_float4(h0[0], h0[1], h0[2], h0[3]);
                    *(float4*)&hb[sA][1][4 * cg] = make_float4(h1[0], h1[1], h1[2], h1[3]);
                    *(float4*)&hb[sA][2][4 * cg] = make_float4(h2[0], h2[1], h2[2], h2[3]);
                    *(float4*)&hb[sA][3][4 * cg] = make_float4(h3[0], h3[1], h3[2], h3[3]);
                }
                __syncthreads();

                // ---------------- Stage B: insert + vertical blur + SSIM ----------------
                {
                    // Insert new h-rows rel 4m+s2 at static slots (4p+s2)&15.
#pragma unroll
                    for (int s2 = 0; s2 < 4; ++s2) {
#pragma unroll
                        for (int f = 0; f < 4; ++f)
                            rg[f][(4 * p + s2) & 15] = hb[s2][f][t];
                    }
#pragma unroll
                    for (int s2 = 0; s2 < 4; ++s2) {
                        const int orel = 4 * m - 10 + s2;
                        float a0 = 0.f, a1 = 0.f, a2 = 0.f, a3 = 0.f;
#pragma unroll
                        for (int k = 0; k < 11; ++k) {
                            const int sl = (4 * p + s2 + k + 6) & 15;
                            a0 = fmaf(w[k], rg[0][sl], a0);
                            a1 = fmaf(w[k], rg[1][sl], a1);
                            a2 = fmaf(w[k], rg[2][sl], a2);
                            a3 = fmaf(w[k], rg[3][sl], a3);
                        }
                        const float mux2 = a0 * a0;
                        const float muy2 = a1 * a1;
                        const float mxy  = a0 * a1;
                        const float sigsum = a2 - mux2 - muy2;  // sigma_x + sigma_y
                        const float sxy    = a3 - mxy;
                        const float num = (2.0f * mxy + C1) * (2.0f * sxy + C2);
                        const float den = (mux2 + muy2 + C1 + EPS) * (sigsum + C2 + EPS);
                        const float v = fmaxf(__fdividef(num, den), 0.0f);
                        if (colok && (orel >= 0) && (orel < hseg)) local += v;
                    }
                }
                __syncthreads();
            }
        }
    }

    // ---------------- block reduction + atomic ----------------
    float v = local;
#pragma unroll
    for (int off = 32; off > 0; off >>= 1) v += __shfl_down(v, off, 64);
    if ((t & 63) == 0) red[t >> 6] = v;
    __syncthreads();
    if (t == 0) {
        atomicAdd(&out[b], (red[0] + red[1] + red[2] + red[3]) * INV_COUNT);
    }
}

extern "C" void kernel_launch(void* const* d_in, const int* in_sizes, int n_in,
                              void* d_out, int out_size, void* d_ws, size_t ws_size,
                              hipStream_t stream) {
    const float* X  = (const float*)d_in[0];
    const float* Y  = (const float*)d_in[1];
    const float* Wg = (const float*)d_in[2];
    float* out = (float*)d_out;

    hipLaunchKernelGGL(ssim_zero_out, dim3(1), dim3(64), 0, stream, out);
    hipLaunchKernelGGL(ssim_fused, dim3(16 * 3 * 3 * NSEG), dim3(256), 0, stream,
                       X, Y, Wg, out);
}